// Round 1
// 1818.003 us; speedup vs baseline: 1.0715x; 1.0715x over previous
//
#include <hip/hip_runtime.h>
#include <hip/hip_fp16.h>

#define DT 5e-5f
#define SPRING_Y 30000.0f
#define DASHPOT 100.0f
// exp(-DT * DRAG_DAMPING) = exp(-5e-5)
#define DRAG 0.9999500012499792f

// xv layout: xv[2*i] = position, xv[2*i+1] = velocity (w unused).
// 32B per vertex, 32B-aligned -> both halves in ONE 64B line.
// adj entry: 4 BYTES: (neighbor_idx:17) << 15 | (fp16(1/rest) & 0x7fff).
// Stride layout: vertex v's entries at adj[v*64 .. v*64+deg[v]).
// Fill is SLICE-OWNED: 8 vertex slices (~3.2MB of adj each, one XCD-L2 worth);
// block b handles spring chunk b>>3 and writes only endpoints in slice b&7.
// substep: 8 lanes/vertex; lane pairs fetch each 64B xv line cooperatively.
// R11: latency-bound inner loop restructured for MLP — both pair lanes load
// BOTH pair adj entries (kills the pre-gather shfl on the critical path),
// counted loop, 2 pair-steps per superiteration so 4 adj loads + 4 line
// gathers are all in flight before any compute. Per-lane FP order unchanged.

// ---------- one-time (per launch) build ----------

__global__ void init_k(const float* __restrict__ x0, float4* __restrict__ xv,
                       int* __restrict__ deg, int nv) {
    int i = blockIdx.x * blockDim.x + threadIdx.x;
    if (i < nv) {
        xv[2 * i]     = make_float4(x0[3 * i], x0[3 * i + 1], x0[3 * i + 2], 0.0f);
        xv[2 * i + 1] = make_float4(0.0f, 0.0f, 0.0f, 0.0f);
        deg[i] = 0;
    }
}

__global__ void fill_sliced_k(const int2* __restrict__ springs,
                              const float* __restrict__ rest,
                              int* __restrict__ deg, unsigned* __restrict__ adj,
                              int ns, int nv, int S) {
    int b = blockIdx.x;
    int slice = b & 7;
    int s = (b >> 3) * blockDim.x + threadIdx.x;
    if (s >= ns) return;

    int lo = (int)(((long long)slice * nv) >> 3);
    int hi = (int)(((long long)(slice + 1) * nv) >> 3);

    int2 p = springs[s];
    unsigned h = __half_as_ushort(__float2half(1.0f / rest[s])) & 0x7fffu;
    if (p.x >= lo && p.x < hi) {
        int a = atomicAdd(&deg[p.x], 1);
        adj[p.x * S + a] = ((unsigned)p.y << 15) | h;
    }
    if (p.y >= lo && p.y < hi) {
        int c = atomicAdd(&deg[p.y], 1);
        adj[p.y * S + c] = ((unsigned)p.x << 15) | h;
    }
}

// ---------- fused per-substep kernel ----------

// one pair-step: lane computes its OWN entry's spring contribution.
// t1 = xvin[2*nA + par]  (even lane: pos(A); odd lane: vel(A))
// t2 = xvin[2*nB + 1-par](even lane: vel(B); odd lane: pos(B))
__device__ __forceinline__ void spring_accum(
        int par, unsigned e, float msk, float4 t1, float4 t2,
        const float4& xa, const float4& va,
        float& fx, float& fy, float& fz) {
    float invr = __uint_as_float(((e & 0x7fffu) << 13) + (112u << 23));
    float4 xb, u;
    xb.x = par ? t2.x : t1.x;          // own neighbor's position
    xb.y = par ? t2.y : t1.y;
    xb.z = par ? t2.z : t1.z;
    u.x  = par ? t1.x : t2.x;          // half this lane must SEND (partner's vel)
    u.y  = par ? t1.y : t2.y;
    u.z  = par ? t1.z : t2.z;
    float vbx = __shfl_xor(u.x, 1);    // own neighbor's velocity
    float vby = __shfl_xor(u.y, 1);
    float vbz = __shfl_xor(u.z, 1);

    float dx = xb.x - xa.x, dy = xb.y - xa.y, dz = xb.z - xa.z;
    float len = sqrtf(dx * dx + dy * dy + dz * dz);
    float il = 1.0f / len;             // clamped dups are valid entries: len > 0
    float ddx = dx * il, ddy = dy * il, ddz = dz * il;
    float vrel = (vbx - va.x) * ddx + (vby - va.y) * ddy + (vbz - va.z) * ddz;
    float coef = (SPRING_Y * (len * invr - 1.0f) + DASHPOT * vrel) * msk;
    fx += coef * ddx;
    fy += coef * ddy;
    fz += coef * ddz;
}

__global__ void __launch_bounds__(256) substep_k(
        const float4* __restrict__ xvin, float4* __restrict__ xvout,
        const unsigned* __restrict__ adj, const int* __restrict__ deg,
        const float* __restrict__ mass, int nv, int S,
        float* __restrict__ out) {
    int gid = blockIdx.x * blockDim.x + threadIdx.x;
    int vid = gid >> 3;
    int sub = gid & 7;
    if (vid >= nv) return;

    float4 xa = xvin[2 * vid];
    float4 va = xvin[2 * vid + 1];
    float m  = mass[vid];              // hoisted: overlaps with loop latency
    int d  = deg[vid];
    int s0 = vid * S;
    int last = s0 + d - 1;             // valid when d > 0
    int par  = sub & 1;                // lane parity within its pair
    int base = sub & ~1;               // pair's entry offset within the row
    int niter = (d > base) ? ((d - base + 7) >> 3) : 0;  // pair-steps (uniform in pair)
    int pf = s0 + base;

    float fx = 0.0f, fy = 0.0f, fz = 0.0f;

    // 2 pair-steps per superiteration: 4 adj loads + 4 line-gathers all
    // issue before any shuffle/compute -> 2x fewer serial latency chains.
    for (int u = 0; u < niter; u += 2) {
        int pb0 = pf + 8 * u;
        int pb1 = pb0 + 8;
        // both lanes of the pair load BOTH entries (same cache line, clamped:
        // never touches uninitialized adj slots)
        unsigned eA0 = adj[min(pb0,     last)];
        unsigned eB0 = adj[min(pb0 + 1, last)];
        unsigned eA1 = adj[min(pb1,     last)];
        unsigned eB1 = adj[min(pb1 + 1, last)];
        int nA0 = (int)(eA0 >> 15), nB0 = (int)(eB0 >> 15);
        int nA1 = (int)(eA1 >> 15), nB1 = (int)(eB1 >> 15);

        // cooperative line fetches, all independent (masked steps re-fetch the
        // clamped line -> L1 hit)
        float4 t10 = xvin[2 * nA0 + par];
        float4 t20 = xvin[2 * nB0 + (1 - par)];
        float4 t11 = xvin[2 * nA1 + par];
        float4 t21 = xvin[2 * nB1 + (1 - par)];

        {   // step 0
            float msk = (pb0 + par <= last) ? 1.0f : 0.0f;
            spring_accum(par, par ? eB0 : eA0, msk, t10, t20, xa, va, fx, fy, fz);
        }
        {   // step 1 (fully masked when niter is odd and u+1 == niter)
            float msk = (pb1 + par <= last) ? 1.0f : 0.0f;
            spring_accum(par, par ? eB1 : eA1, msk, t11, t21, xa, va, fx, fy, fz);
        }
    }

    // reduce across the 8 lanes of this vertex (xor stays within the group)
    fx += __shfl_xor(fx, 1);
    fx += __shfl_xor(fx, 2);
    fx += __shfl_xor(fx, 4);
    fy += __shfl_xor(fy, 1);
    fy += __shfl_xor(fy, 2);
    fy += __shfl_xor(fy, 4);
    fz += __shfl_xor(fz, 1);
    fz += __shfl_xor(fz, 2);
    fz += __shfl_xor(fz, 4);

    if (sub == 0) {
        fz += m * (-9.8f);
        float invm = 1.0f / m;

        va.x = (va.x + DT * fx * invm) * DRAG;
        va.y = (va.y + DT * fy * invm) * DRAG;
        va.z = (va.z + DT * fz * invm) * DRAG;

        xa.x += DT * va.x;
        xa.y += DT * va.y;
        xa.z += DT * va.z;
        xa.z = fmaxf(xa.z, 0.0f);
        if (xa.z == 0.0f) va.z = 0.0f;

        xvout[2 * vid]     = xa;
        xvout[2 * vid + 1] = va;

        if (out) {                     // final substep: emit packed (NV,3) output
            out[3 * vid + 0] = xa.x;
            out[3 * vid + 1] = xa.y;
            out[3 * vid + 2] = xa.z;
        }
    }
}

extern "C" void kernel_launch(void* const* d_in, const int* in_sizes, int n_in,
                              void* d_out, int out_size, void* d_ws, size_t ws_size,
                              hipStream_t stream) {
    const float* x0      = (const float*)d_in[0];   // (NV,3) fp32
    const int2*  springs = (const int2*)d_in[1];    // (NS,2) int32
    const float* rest    = (const float*)d_in[2];   // (NS,)  fp32
    const float* mass    = (const float*)d_in[3];   // (NV,)  fp32

    const int ns = in_sizes[2];        // 1,000,000
    const int nv = in_sizes[3];        // 100,000
    const int nb = (nv + 255) / 256;

    // workspace layout
    char* ws = (char*)d_ws;
    size_t o = 0;
    float4* xva   = (float4*)(ws + o); o += (size_t)nv * 32;   // x,v interleaved
    float4* xvb   = (float4*)(ws + o); o += (size_t)nv * 32;
    int* deg      = (int*)(ws + o);    o += (((size_t)nv * 4 + 15) & ~15ull);
    unsigned* adj = (unsigned*)(ws + o);                        // nv*64*4B = 25.6 MB

    const int STRIDE = 64;

    dim3 blk(256);
    dim3 vgrid(nb);
    dim3 fgrid(8 * ((ns + 255) / 256));           // 8 slices x spring chunks
    dim3 subgrid(((size_t)nv * 8 + 255) / 256);   // 8 lanes per vertex

    // one-time build (replayed every call; amortized over 100 substeps)
    init_k<<<vgrid, blk, 0, stream>>>(x0, xva, deg, nv);
    fill_sliced_k<<<fgrid, blk, 0, stream>>>(springs, rest, deg, adj, ns, nv, STRIDE);

    const int NSUB = 100;
    float4* xi = xva;
    float4* xo = xvb;
    for (int t = 0; t < NSUB; ++t) {
        float* out = (t == NSUB - 1) ? (float*)d_out : nullptr;
        substep_k<<<subgrid, blk, 0, stream>>>(xi, xo, adj, deg, mass, nv, STRIDE, out);
        float4* tmp = xi; xi = xo; xo = tmp;
    }
}